// Round 5
// baseline (1229.701 us; speedup 1.0000x reference)
//
#include <hip/hip_runtime.h>
#include <cstdint>

#define NTOK 4096
#define DDIM 1024
#define HDIM 4096
#define ODIM 1024
#define NEXP 8
#define NSLOT (2*NTOK)
#define MAXT128 72
#define MAXT256 40

typedef __bf16 bf16x8 __attribute__((ext_vector_type(8)));
typedef float  f32x4  __attribute__((ext_vector_type(4)));
typedef unsigned short ushort8v __attribute__((ext_vector_type(8)));

__device__ __forceinline__ unsigned short f2bf(float f) {
    union { float f; unsigned int u; } v; v.f = f;
    unsigned int r = (v.u + 0x7FFF + ((v.u >> 16) & 1)) >> 16;
    return (unsigned short)r;
}

// ---- gate: logits = relu(x@Wg), top-2 (lowest-index tie-break), fused x->bf16 cast ----
__global__ void gate_kernel(const float* __restrict__ x, const float* __restrict__ Wg,
                            int2* __restrict__ sel, float2* __restrict__ wts,
                            int* __restrict__ counts, unsigned short* __restrict__ xb) {
    int wave = threadIdx.x >> 6;
    int lane = threadIdx.x & 63;
    int n = blockIdx.x * 4 + wave;
    float acc[NEXP];
#pragma unroll
    for (int e = 0; e < NEXP; e++) acc[e] = 0.f;
    const float* xr = x + (size_t)n * DDIM;
    unsigned short* xbr = xb + (size_t)n * DDIM;
#pragma unroll
    for (int i = 0; i < 4; i++) {
        int d = i * 256 + lane * 4;
        float4 xv = *(const float4*)&xr[d];
        ushort4 o;
        o.x = f2bf(xv.x); o.y = f2bf(xv.y); o.z = f2bf(xv.z); o.w = f2bf(xv.w);
        *(ushort4*)&xbr[d] = o;
        const float* wr = Wg + (size_t)d * NEXP;
#pragma unroll
        for (int jj = 0; jj < 4; jj++) {
            float xs = (jj == 0) ? xv.x : (jj == 1) ? xv.y : (jj == 2) ? xv.z : xv.w;
#pragma unroll
            for (int e = 0; e < NEXP; e++)
                acc[e] = fmaf(xs, wr[jj * NEXP + e], acc[e]);
        }
    }
#pragma unroll
    for (int e = 0; e < NEXP; e++) {
#pragma unroll
        for (int off = 32; off >= 1; off >>= 1)
            acc[e] += __shfl_xor(acc[e], off, 64);
    }
    if (lane == 0) {
        float l0 = -1e30f, l1 = -1e30f; int e0 = 0, e1 = 0;
#pragma unroll
        for (int e = 0; e < NEXP; e++) {
            float v = fmaxf(acc[e], 0.f);     // relu before softmax
            if (v > l0)      { l1 = l0; e1 = e0; l0 = v; e0 = e; }
            else if (v > l1) { l1 = v;  e1 = e; }
        }
        float w0 = 1.f / (1.f + expf(l1 - l0));   // softmax Z cancels in top-2 renorm
        sel[n] = make_int2(e0, e1);
        wts[n] = make_float2(w0, 1.f - w0);
        atomicAdd(&counts[e0], 1);
        atomicAdd(&counts[e1], 1);
    }
}

// ---- route: scan counts -> offsets + 128-tile and 256-tile tables, slot assignment ----
__global__ void route_kernel(const int2* __restrict__ sel, const float2* __restrict__ wts,
                             const int* __restrict__ counts, int* __restrict__ offsets,
                             int4* __restrict__ t128, int* __restrict__ nt128,
                             int4* __restrict__ t256, int* __restrict__ nt256,
                             int* __restrict__ slot_token, float* __restrict__ slot_weight) {
    __shared__ int cur[NEXP];
    int t = threadIdx.x;
    if (t == 0) {
        int s = 0, n1 = 0, n2 = 0;
        for (int e = 0; e < NEXP; e++) {
            offsets[e] = s; cur[e] = s;
            int c = counts[e];
            for (int r = 0; r < c; r += 128)
                t128[n1++] = make_int4(e, s + r, min(128, c - r), 0);
            for (int r = 0; r < c; r += 256)
                t256[n2++] = make_int4(e, s + r, min(256, c - r), 0);
            s += c;
        }
        offsets[NEXP] = s;
        *nt128 = n1; *nt256 = n2;
    }
    __syncthreads();
    for (int n = t; n < NTOK; n += blockDim.x) {
        int2 se = sel[n]; float2 w = wts[n];
        int p0 = atomicAdd(&cur[se.x], 1);
        slot_token[p0] = n; slot_weight[p0] = w.x;
        int p1 = atomicAdd(&cur[se.y], 1);
        slot_token[p1] = n; slot_weight[p1] = w.y;
    }
}

// ---- transpose+cast: src [R][C] fp32 -> dst [C][R] bf16, per expert (z) ----
__global__ void transpose_cast_kernel(const float* __restrict__ src, unsigned short* __restrict__ dst,
                                      int R, int C) {
    __shared__ float tile[64][65];
    int e = blockIdx.z;
    const float* s = src + (size_t)e * R * C;
    unsigned short* d = dst + (size_t)e * R * C;
    int t = threadIdx.x;                      // 256 threads
    int r0 = blockIdx.y * 64, c0 = blockIdx.x * 64;
#pragma unroll
    for (int p = 0; p < 4; p++) {
        int r = p * 16 + (t >> 4);
        int c = (t & 15) * 4;
        float4 v = *(const float4*)&s[(size_t)(r0 + r) * C + (c0 + c)];
        tile[r][c] = v.x; tile[r][c + 1] = v.y; tile[r][c + 2] = v.z; tile[r][c + 3] = v.w;
    }
    __syncthreads();
    int c = t >> 2, rb = (t & 3) * 16;
#pragma unroll
    for (int j = 0; j < 2; j++) {
        ushort8v v;
#pragma unroll
        for (int i = 0; i < 8; i++) v[i] = f2bf(tile[rb + j * 8 + i][c]);
        *(ushort8v*)&d[(size_t)(c0 + c) * R + (r0 + rb + j * 8)] = v;
    }
}

// ---- register-staged pipelined MFMA GEMM: TM x TN tile, BK=32, SINGLE LDS buffer ----
// Staging path: global_load_dwordx4 -> VGPR -> ds_write_b128.  Compute's ds_reads no
// longer depend on in-flight global loads (no vmcnt(0) drain per iter); the vmcnt wait
// sits at the ds_write of tile k+1, issued one full iteration earlier.
// MODE 1 (128x256): grid=(NDIM/TN, MAXT128); A gathered via slot_token; epi:+b1,relu,bf16 h
// MODE 2 (256x128): grid=(8, MAXT256); tile=x+8*(y>>3), col=y&7; epi:+b2,relu,*w,atomic out
template <int MODE, int KDIM, int NDIM, int TM, int TN, int WMv>
__global__ __launch_bounds__(256, 2) void moe_gemm_kernel(
    const unsigned short* __restrict__ A,
    const unsigned short* __restrict__ B,
    const float* __restrict__ bias,
    const int4* __restrict__ tile_meta,
    const int* __restrict__ ntiles,
    const int* __restrict__ slot_token,
    const float* __restrict__ slot_weight,
    unsigned short* __restrict__ h,
    float* __restrict__ out) {

    int tileIdx, colBase;
    if constexpr (MODE == 1) {
        tileIdx = blockIdx.y;
        colBase = blockIdx.x * TN;
    } else {
        int j = blockIdx.y;
        tileIdx = blockIdx.x + 8 * (j >> 3);
        colBase = (j & 7) * TN;
    }
    if (tileIdx >= *ntiles) return;
    int4 tm = tile_meta[tileIdx];
    int e = tm.x, slotBase = tm.y, rows = tm.z;

    constexpr int PA = TM / 64;                // A staging passes (rows per pass: 64)
    constexpr int PB = TN / 64;
    constexpr int NI = KDIM / 32;

    __shared__ __align__(16) unsigned short As[TM * 32];
    __shared__ __align__(16) unsigned short Bs[TN * 32];

    int tid = threadIdx.x;
    int w = tid >> 6, l = tid & 63;
    int quad = l >> 4, lr = l & 15;
    int wm = w % WMv, wn = w / WMv;

    int rl = tid >> 2;                         // staging row within a 64-row pass
    int u  = tid & 3;                          // global 16B unit within 64B row
    int us = u ^ ((rl >> 1) & 3);              // swizzled LDS slot unit

    const unsigned short* aq[PA]; int wa[PA];
    const unsigned short* bq[PB]; int wb[PB];
    const unsigned short* Be = B + (size_t)e * NDIM * KDIM;
#pragma unroll
    for (int p = 0; p < PA; p++) {
        int r = p * 64 + rl;
        int slot = min(slotBase + r, NSLOT - 1);
        if constexpr (MODE == 1) {
            int tok = slot_token[slot];
            aq[p] = A + (size_t)tok * KDIM + u * 8;
        } else {
            aq[p] = A + (size_t)slot * KDIM + u * 8;
        }
        wa[p] = r * 64 + us * 16;              // LDS byte offset
    }
#pragma unroll
    for (int p = 0; p < PB; p++) {
        int r = p * 64 + rl;
        bq[p] = Be + (size_t)(colBase + r) * KDIM + u * 8;
        wb[p] = r * 64 + us * 16;
    }

    f32x4 zero = {0.f, 0.f, 0.f, 0.f};
    f32x4 acc[8][4];
#pragma unroll
    for (int m = 0; m < 8; m++)
#pragma unroll
        for (int n = 0; n < 4; n++) acc[m][n] = zero;

    int su = (quad ^ ((lr >> 1) & 3)) * 16;    // swizzled byte offset within 64B row

    uint4 ra[PA], rb[PB];
    auto gload = [&](int k) {
#pragma unroll
        for (int p = 0; p < PA; p++) ra[p] = *(const uint4*)(aq[p] + k * 32);
#pragma unroll
        for (int p = 0; p < PB; p++) rb[p] = *(const uint4*)(bq[p] + k * 32);
    };
    auto dswrite = [&]() {
#pragma unroll
        for (int p = 0; p < PA; p++) *(uint4*)((char*)As + wa[p]) = ra[p];
#pragma unroll
        for (int p = 0; p < PB; p++) *(uint4*)((char*)Bs + wb[p]) = rb[p];
    };
    auto compute = [&]() {
        const char* A_ = (const char*)As;
        const char* B_ = (const char*)Bs;
        bf16x8 af[8], bf[4];
#pragma unroll
        for (int m = 0; m < 8; m++)
            af[m] = *(const bf16x8*)(A_ + (wm * 128 + m * 16 + lr) * 64 + su);
#pragma unroll
        for (int n = 0; n < 4; n++)
            bf[n] = *(const bf16x8*)(B_ + (wn * 64 + n * 16 + lr) * 64 + su);
#pragma unroll
        for (int m = 0; m < 8; m++)
#pragma unroll
            for (int n = 0; n < 4; n++)
                acc[m][n] = __builtin_amdgcn_mfma_f32_16x16x32_bf16(af[m], bf[n], acc[m][n], 0, 0, 0);
    };

    gload(0);
    dswrite();
    gload(1);
    __syncthreads();
    for (int k = 0; k < NI; k++) {
        compute();
        if (k < NI - 1) {
            __syncthreads();                   // all waves done reading LDS tile k
            dswrite();                         // tile k+1 (vmcnt waits only its loads)
            if (k + 2 < NI) gload(k + 2);      // tile k+2 into flight
            __syncthreads();                   // tile k+1 visible
        }
    }

    if constexpr (MODE == 1) {
        const float* bv = bias + e * NDIM;
#pragma unroll
        for (int n = 0; n < 4; n++) {
            int gc = colBase + wn * 64 + n * 16 + lr;
            float b = bv[gc];
#pragma unroll
            for (int m = 0; m < 8; m++) {
                int rloc = wm * 128 + m * 16 + quad * 4;
#pragma unroll
                for (int i = 0; i < 4; i++) {
                    int r = rloc + i;
                    if (r < rows) {
                        float v = fmaxf(acc[m][n][i] + b, 0.f);
                        h[(size_t)(slotBase + r) * NDIM + gc] = f2bf(v);
                    }
                }
            }
        }
    } else {
        const float* bv = bias + e * NDIM;
#pragma unroll
        for (int m = 0; m < 8; m++) {
            int rloc = wm * 128 + m * 16 + quad * 4;
#pragma unroll
            for (int i = 0; i < 4; i++) {
                int r = rloc + i;
                if (r >= rows) continue;
                int s = slotBase + r;
                int tok = slot_token[s];
                float wgt = slot_weight[s];
                float* orow = out + (size_t)tok * ODIM;
#pragma unroll
                for (int n = 0; n < 4; n++) {
                    int gc = colBase + wn * 64 + n * 16 + lr;
                    float v = fmaxf(acc[m][n][i] + bv[gc], 0.f) * wgt;
                    atomicAdd(&orow[gc], v);
                }
            }
        }
    }
}

extern "C" void kernel_launch(void* const* d_in, const int* in_sizes, int n_in,
                              void* d_out, int out_size, void* d_ws, size_t ws_size,
                              hipStream_t stream) {
    const float* x  = (const float*)d_in[0];
    const float* Wg = (const float*)d_in[1];
    const float* W1 = (const float*)d_in[2];
    const float* b1 = (const float*)d_in[3];
    const float* W2 = (const float*)d_in[4];
    const float* b2 = (const float*)d_in[5];
    float* out = (float*)d_out;

    char* ws = (char*)d_ws;
    int*    counts      = (int*)(ws + 0);
    int*    offsets     = (int*)(ws + 64);
    int*    nt128       = (int*)(ws + 128);
    int*    nt256       = (int*)(ws + 132);
    int4*   t128        = (int4*)(ws + 256);
    int4*   t256        = (int4*)(ws + 2048);
    int2*   sel         = (int2*)(ws + 4096);
    float2* wts         = (float2*)(ws + 36864);
    int*    slot_token  = (int*)(ws + 69632);
    float*  slot_weight = (float*)(ws + 102400);
    unsigned short* xb  = (unsigned short*)(ws + 2097152);   //  8 MiB [NTOK][D]
    unsigned short* W1T = (unsigned short*)(ws + 10485760);  // 64 MiB [E][H][D]
    unsigned short* W2T = (unsigned short*)(ws + 77594624);  // 64 MiB [E][O][H]
    unsigned short* hbf = (unsigned short*)(ws + 144703488); // 64 MiB [NSLOT][H]

    hipMemsetAsync(d_out, 0, (size_t)NTOK * ODIM * sizeof(float), stream);
    hipMemsetAsync(ws, 0, 256, stream);

    gate_kernel<<<NTOK / 4, 256, 0, stream>>>(x, Wg, sel, wts, counts, xb);
    route_kernel<<<1, 512, 0, stream>>>(sel, wts, counts, offsets, t128, nt128, t256, nt256,
                                        slot_token, slot_weight);

    transpose_cast_kernel<<<dim3(HDIM / 64, DDIM / 64, NEXP), 256, 0, stream>>>(W1, W1T, DDIM, HDIM);
    transpose_cast_kernel<<<dim3(ODIM / 64, HDIM / 64, NEXP), 256, 0, stream>>>(W2, W2T, HDIM, ODIM);

    // GEMM1: 128x256 tiles, waves 1x4; colblock<->XCD affinity (16 % 8 == 0)
    moe_gemm_kernel<1, DDIM, HDIM, 128, 256, 1><<<dim3(HDIM / 256, MAXT128), 256, 0, stream>>>(
        xb, W1T, b1, t128, nt128, slot_token, slot_weight, hbf, nullptr);
    // GEMM2: 256x128 tiles, waves 2x2; per-XCD tile ownership, cols inner
    moe_gemm_kernel<2, HDIM, ODIM, 256, 128, 2><<<dim3(8, MAXT256), 256, 0, stream>>>(
        hbf, W2T, b2, t256, nt256, slot_token, slot_weight, nullptr, out);
}